// Round 10
// baseline (5980.305 us; speedup 1.0000x reference)
//
#include <hip/hip_runtime.h>
#include <hip/hip_bf16.h>

#define NN 100000      // nodes
#define BG 500         // graphs
#define NPG 200        // nodes per graph
#define KTOP 30
#define FCAT 97
#define NCLS 10

typedef long long i64;

// ---------------------------------------------------------------------------
// runtime dtype probes (harness staging behavior is under-documented; detect)
// flags[0] = edges are int64 (else int32); flags[1] = floats are bf16 (else fp32)
// ---------------------------------------------------------------------------
__global__ void detect_dtypes(const void* __restrict__ ei, const void* __restrict__ xp,
                              int* __restrict__ flags) {
    if (threadIdx.x != 0) return;
    const i64* p = (const i64*)ei;
    int ok = 1;
    for (int i = 0; i < 64; ++i) {
        i64 v = p[i];
        if (v < 0 || v >= NN) { ok = 0; break; }
    }
    flags[0] = ok;
    // fp32-staged N(0,1) data: low 16-bit halves have random exponent bits
    const unsigned short* u = (const unsigned short*)xp;
    int crazy = 0;
    for (int i = 0; i < 256; ++i) {
        int ex = (u[i] >> 7) & 0xFF;
        if (ex == 0xFF || ex > 150) crazy++;
    }
    flags[1] = (crazy < 8) ? 1 : 0;
}

__device__ __forceinline__ int edge_at(const void* ei, int is64, size_t pos) {
    return is64 ? (int)((const i64*)ei)[pos] : ((const int*)ei)[pos];
}

__device__ __forceinline__ float fld(const void* p, int isbf, size_t i) {
    return isbf ? __bfloat162float(((const __hip_bfloat16*)p)[i])
                : ((const float*)p)[i];
}

// ---------------------------------------------------------------------------
// degree / normalization
// ---------------------------------------------------------------------------
__global__ void count_deg(const void* __restrict__ ei, const int* __restrict__ flags,
                          int* __restrict__ deg, int E) {
    int e = blockIdx.x * 256 + threadIdx.x;
    if (e < E) {
        int d = edge_at(ei, flags[0], (size_t)E + e);
        atomicAdd(&deg[d], 1);
    }
}

__global__ void make_dis(const int* __restrict__ deg, float* __restrict__ dis, int n) {
    int i = blockIdx.x * 256 + threadIdx.x;
    if (i < n) dis[i] = rsqrtf((float)deg[i] + 1.0f);
}

// ---------------------------------------------------------------------------
// layer linears. Each writes h (dense [N,32]) AND pre-initializes the xcat
// column slice with the self-loop term h*dis^2.
// ---------------------------------------------------------------------------
__global__ __launch_bounds__(256) void lin128x32(const void* __restrict__ x,
                                                 const void* __restrict__ W,
                                                 const int* __restrict__ flags,
                                                 const float* __restrict__ dis,
                                                 float* __restrict__ h,
                                                 float* __restrict__ xcat) {
    __shared__ float wS[128 * 32];
    __shared__ float xS[8][128];
    int tid = threadIdx.x;
    int isbf = flags[1];
    for (int i = tid; i < 128 * 32; i += 256) wS[i] = fld(W, isbf, i);
    int n0 = blockIdx.x * 8;
    for (int i = tid; i < 8 * 128; i += 256) {
        int r = i >> 7, c = i & 127;
        int n = n0 + r;
        xS[r][c] = (n < NN) ? fld(x, isbf, (size_t)n * 128 + c) : 0.f;
    }
    __syncthreads();
    int r = tid >> 5, c = tid & 31;
    int n = n0 + r;
    if (n < NN) {
        float acc = 0.f;
        #pragma unroll
        for (int k = 0; k < 128; ++k) acc += xS[r][k] * wS[k * 32 + c];
        h[n * 32 + c] = acc;
        float d = dis[n];
        xcat[n * FCAT + c] = acc * d * d;   // col0 = 0
    }
}

__global__ __launch_bounds__(256) void lin32x32(const float* __restrict__ xcat_in,
                                                int col0in,
                                                const void* __restrict__ W,
                                                const int* __restrict__ flags,
                                                const float* __restrict__ dis,
                                                float* __restrict__ h,
                                                float* __restrict__ xcat,
                                                int col0out) {
    __shared__ float wS[32 * 32];
    __shared__ float xS[8][32];
    int tid = threadIdx.x;
    int isbf = flags[1];
    for (int i = tid; i < 32 * 32; i += 256) wS[i] = fld(W, isbf, i);
    int r = tid >> 5, c = tid & 31;
    int n = blockIdx.x * 8 + r;
    xS[r][c] = (n < NN) ? xcat_in[n * FCAT + col0in + c] : 0.f;
    __syncthreads();
    if (n < NN) {
        float acc = 0.f;
        #pragma unroll
        for (int k = 0; k < 32; ++k) acc += xS[r][k] * wS[k * 32 + c];
        h[n * 32 + c] = acc;
        float d = dis[n];
        xcat[n * FCAT + col0out + c] = acc * d * d;
    }
}

__global__ __launch_bounds__(256) void lin32x1(const float* __restrict__ xcat_in,
                                               const void* __restrict__ W,
                                               const int* __restrict__ flags,
                                               const float* __restrict__ dis,
                                               float* __restrict__ h1,
                                               float* __restrict__ xcat) {
    __shared__ float wS[32];
    if (threadIdx.x < 32) wS[threadIdx.x] = fld(W, flags[1], threadIdx.x);
    __syncthreads();
    int n = blockIdx.x * 256 + threadIdx.x;
    if (n < NN) {
        const float* xr = xcat_in + n * FCAT + 64;
        float acc = 0.f;
        #pragma unroll
        for (int k = 0; k < 32; ++k) acc += xr[k] * wS[k];
        h1[n] = acc;
        float d = dis[n];
        xcat[n * FCAT + 96] = acc * d * d;
    }
}

// ---------------------------------------------------------------------------
// edge aggregation: xcat[dst, col0:col0+32] += h[src] * dis[src]*dis[dst]
// ---------------------------------------------------------------------------
__global__ __launch_bounds__(256) void edge_agg32(const void* __restrict__ ei,
                                                  const int* __restrict__ flags,
                                                  const float* __restrict__ dis,
                                                  const float* __restrict__ h,
                                                  float* __restrict__ xcat,
                                                  int col0, int E) {
    int e = blockIdx.x * 32 + (threadIdx.x >> 3);
    if (e >= E) return;
    int f = flags[0];
    int lane = threadIdx.x & 7;
    int s = edge_at(ei, f, (size_t)e);
    int d = edge_at(ei, f, (size_t)E + e);
    float w = dis[s] * dis[d];
    const float4 hv = *(const float4*)(h + s * 32 + lane * 4);
    float* ap = xcat + (size_t)d * FCAT + col0 + lane * 4;
    atomicAdd(ap + 0, hv.x * w);
    atomicAdd(ap + 1, hv.y * w);
    atomicAdd(ap + 2, hv.z * w);
    atomicAdd(ap + 3, hv.w * w);
}

__global__ __launch_bounds__(256) void edge_agg1(const void* __restrict__ ei,
                                                 const int* __restrict__ flags,
                                                 const float* __restrict__ dis,
                                                 const float* __restrict__ h1,
                                                 float* __restrict__ xcat, int E) {
    int e = blockIdx.x * 256 + threadIdx.x;
    if (e < E) {
        int f = flags[0];
        int s = edge_at(ei, f, (size_t)e);
        int d = edge_at(ei, f, (size_t)E + e);
        atomicAdd(&xcat[(size_t)d * FCAT + 96], h1[s] * dis[s] * dis[d]);
    }
}

// ---------------------------------------------------------------------------
// tanh + bias, in place on the xcat column slice
// ---------------------------------------------------------------------------
__global__ __launch_bounds__(256) void tanhize32(float* __restrict__ xcat, int col0,
                                                 const void* __restrict__ b,
                                                 const int* __restrict__ flags) {
    int t = blockIdx.x * 256 + threadIdx.x;
    if (t < NN * 32) {
        int n = t >> 5, c = t & 31;
        size_t idx = (size_t)n * FCAT + col0 + c;
        xcat[idx] = tanhf(xcat[idx] + fld(b, flags[1], c));
    }
}

__global__ __launch_bounds__(256) void tanhize1(float* __restrict__ xcat,
                                                const void* __restrict__ b,
                                                const int* __restrict__ flags) {
    int n = blockIdx.x * 256 + threadIdx.x;
    if (n < NN) {
        size_t idx = (size_t)n * FCAT + 96;
        xcat[idx] = tanhf(xcat[idx] + fld(b, flags[1], 0));
    }
}

// ---------------------------------------------------------------------------
// fused head: per-graph sort-pool(k=30) + conv5 + maxpool + conv6 + fc1 + fc2
// one 256-thread block per graph. NOTE: every work list > 256 items MUST be a
// strided loop — conv5 (480) and conv6 (352) were silently truncated before.
// ---------------------------------------------------------------------------
__device__ __forceinline__ bool before_desc(float av, int ai, float bv, int bi) {
    return (av > bv) || (av == bv && ai < bi);
}

__global__ __launch_bounds__(256) void head_kernel(
        const float* __restrict__ xcat, const int* __restrict__ flags,
        const void* __restrict__ w5, const void* __restrict__ b5,
        const void* __restrict__ w6, const void* __restrict__ b6,
        const void* __restrict__ fw1, const void* __restrict__ fb1,
        const void* __restrict__ fw2, const void* __restrict__ fb2,
        float* __restrict__ out) {
    __shared__ float sval[256];
    __shared__ int   sidx[256];
    __shared__ float tk[KTOP][101];     // padded stride
    __shared__ float w5S[16 * 97];
    __shared__ float b5S[16];
    __shared__ float w6S[32 * 80];
    __shared__ float b6S[32];
    __shared__ float o5[16][30];
    __shared__ float m6[16][15];
    __shared__ float t6[352];
    __shared__ float hfc[128];

    int g = blockIdx.x;
    int tid = threadIdx.x;
    int isbf = flags[1];

    for (int i = tid; i < 16 * 97; i += 256) w5S[i] = fld(w5, isbf, i);
    for (int i = tid; i < 32 * 80; i += 256) w6S[i] = fld(w6, isbf, i);
    if (tid < 16) b5S[tid] = fld(b5, isbf, tid);
    if (tid < 32) b6S[tid] = fld(b6, isbf, tid);

    float v = -INFINITY;
    if (tid < NPG) v = xcat[(size_t)(g * NPG + tid) * FCAT + 96];
    sval[tid] = v;
    sidx[tid] = tid;
    __syncthreads();

    // bitonic sort, 256 elems, descending / stable (index tiebreak)
    for (int k = 2; k <= 256; k <<= 1) {
        for (int j = k >> 1; j > 0; j >>= 1) {
            int i = tid;
            int ixj = i ^ j;
            if (ixj > i) {
                float av = sval[i], bv = sval[ixj];
                int   ai = sidx[i], bi = sidx[ixj];
                bool dir = ((i & k) == 0);
                bool sw = dir ? before_desc(bv, bi, av, ai)
                              : before_desc(av, ai, bv, bi);
                if (sw) {
                    sval[i] = bv; sval[ixj] = av;
                    sidx[i] = bi; sidx[ixj] = ai;
                }
            }
            __syncthreads();
        }
    }

    // gather top-30 rows
    for (int i = tid; i < KTOP * FCAT; i += 256) {
        int k = i / FCAT, f = i % FCAT;
        tk[k][f] = xcat[(size_t)(g * NPG + sidx[k]) * FCAT + f];
    }
    __syncthreads();

    // conv5: per-row dot with 16 filters, relu  (480 items -> strided loop!)
    for (int t = tid; t < 16 * 30; t += 256) {
        int o = t / 30, p = t % 30;
        float acc = b5S[o];
        #pragma unroll 4
        for (int f = 0; f < 97; ++f) acc += tk[p][f] * w5S[o * 97 + f];
        o5[o][p] = fmaxf(acc, 0.f);
    }
    __syncthreads();

    // maxpool(2,2): 240 items
    if (tid < 16 * 15) {
        int o = tid / 15, q = tid % 15;
        m6[o][q] = fmaxf(o5[o][2 * q], o5[o][2 * q + 1]);
    }
    __syncthreads();

    // conv6: Conv1d(16,32,5), relu  (352 items -> strided loop!)
    for (int t = tid; t < 32 * 11; t += 256) {
        int o = t / 11, p = t % 11;
        float acc = b6S[o];
        #pragma unroll
        for (int i = 0; i < 16; ++i)
            #pragma unroll
            for (int j = 0; j < 5; ++j)
                acc += m6[i][p + j] * w6S[o * 80 + i * 5 + j];
        t6[o * 11 + p] = fmaxf(acc, 0.f);
    }
    __syncthreads();

    // fc1: 352 -> 128, relu
    if (tid < 128) {
        float acc = fld(fb1, isbf, tid);
        for (int i = 0; i < 352; ++i)
            acc += t6[i] * fld(fw1, isbf, (size_t)tid * 352 + i);
        hfc[tid] = fmaxf(acc, 0.f);
    }
    __syncthreads();

    // fc2: 128 -> 10, fp32 output (confirmed: harness reads fp32)
    if (tid < NCLS) {
        float acc = fld(fb2, isbf, tid);
        #pragma unroll 4
        for (int i = 0; i < 128; ++i)
            acc += hfc[i] * fld(fw2, isbf, (size_t)tid * 128 + i);
        out[g * NCLS + tid] = acc;
    }
}

// ---------------------------------------------------------------------------
// launch
// ---------------------------------------------------------------------------
extern "C" void kernel_launch(void* const* d_in, const int* in_sizes, int n_in,
                              void* d_out, int out_size, void* d_ws, size_t ws_size,
                              hipStream_t stream) {
    const void* x  = d_in[0];
    const void* ei = d_in[1];
    // d_in[2] = batch (unused: equal-size, sorted graphs)
    const void* W1 = d_in[3];  const void* b1 = d_in[4];
    const void* W2 = d_in[5];  const void* b2 = d_in[6];
    const void* W3 = d_in[7];  const void* b3 = d_in[8];
    const void* W4 = d_in[9];  const void* b4 = d_in[10];
    const void* w5 = d_in[11]; const void* b5 = d_in[12];
    const void* w6 = d_in[13]; const void* b6 = d_in[14];
    const void* fw1 = d_in[15]; const void* fb1 = d_in[16];
    const void* fw2 = d_in[17]; const void* fb2 = d_in[18];

    const int E = in_sizes[1] / 2;

    // workspace carve-up (256B aligned): ~52.5 MB total
    char* ws = (char*)d_ws;
    auto alloc = [&](size_t bytes) {
        void* p = (void*)ws;
        ws += (bytes + 255) & ~(size_t)255;
        return p;
    };
    int*   flags = (int*) alloc(256);                       // dtype flags
    int*   deg   = (int*) alloc((size_t)NN * 4);            // 0.4 MB
    float* dis   = (float*)alloc((size_t)NN * 4);           // 0.4 MB
    float* h     = (float*)alloc((size_t)NN * 32 * 4);      // 12.8 MB
    float* xcat  = (float*)alloc((size_t)NN * FCAT * 4);    // 38.8 MB
    (void)ws_size; (void)n_in; (void)out_size;

    const int TB = 256;
    int nb_nodes = (NN + TB - 1) / TB;
    int nb_edges = (E + TB - 1) / TB;
    int nb_lin   = (NN + 7) / 8;
    int nb_nc    = (NN * 32 + TB - 1) / TB;
    int nb_agg   = (E + 31) / 32;       // 8 threads/edge, 32 edges/block

    detect_dtypes<<<1, 64, 0, stream>>>(ei, x, flags);

    hipMemsetAsync(deg, 0, (size_t)NN * 4, stream);
    count_deg<<<nb_edges, TB, 0, stream>>>(ei, flags, deg, E);
    make_dis<<<nb_nodes, TB, 0, stream>>>(deg, dis, NN);

    // layer 1: 128 -> 32 (cols 0..31)
    lin128x32<<<nb_lin, TB, 0, stream>>>(x, W1, flags, dis, h, xcat);
    edge_agg32<<<nb_agg, TB, 0, stream>>>(ei, flags, dis, h, xcat, 0, E);
    tanhize32<<<nb_nc, TB, 0, stream>>>(xcat, 0, b1, flags);

    // layer 2: 32 -> 32 (cols 32..63)
    lin32x32<<<nb_lin, TB, 0, stream>>>(xcat, 0, W2, flags, dis, h, xcat, 32);
    edge_agg32<<<nb_agg, TB, 0, stream>>>(ei, flags, dis, h, xcat, 32, E);
    tanhize32<<<nb_nc, TB, 0, stream>>>(xcat, 32, b2, flags);

    // layer 3: 32 -> 32 (cols 64..95)
    lin32x32<<<nb_lin, TB, 0, stream>>>(xcat, 32, W3, flags, dis, h, xcat, 64);
    edge_agg32<<<nb_agg, TB, 0, stream>>>(ei, flags, dis, h, xcat, 64, E);
    tanhize32<<<nb_nc, TB, 0, stream>>>(xcat, 64, b3, flags);

    // layer 4: 32 -> 1 (col 96)
    lin32x1<<<nb_nodes, TB, 0, stream>>>(xcat, W4, flags, dis, h, xcat);
    edge_agg1<<<nb_edges, TB, 0, stream>>>(ei, flags, dis, h, xcat, E);
    tanhize1<<<nb_nodes, TB, 0, stream>>>(xcat, b4, flags);

    // fused head
    head_kernel<<<BG, TB, 0, stream>>>(xcat, flags, w5, b5, w6, b6,
                                       fw1, fb1, fw2, fb2,
                                       (float*)d_out);
}

// Round 11
// 926.785 us; speedup vs baseline: 6.4527x; 6.4527x over previous
//
#include <hip/hip_runtime.h>
#include <hip/hip_bf16.h>

#define NN 100000      // nodes
#define BG 500         // graphs
#define NPG 200        // nodes per graph
#define KTOP 30
#define FCAT 97
#define NCLS 10

typedef long long i64;

// ---------------------------------------------------------------------------
// runtime dtype probes: flags[0]=edges int64, flags[1]=floats bf16
// ---------------------------------------------------------------------------
__global__ void detect_dtypes(const void* __restrict__ ei, const void* __restrict__ xp,
                              int* __restrict__ flags) {
    if (threadIdx.x != 0) return;
    const i64* p = (const i64*)ei;
    int ok = 1;
    for (int i = 0; i < 64; ++i) {
        i64 v = p[i];
        if (v < 0 || v >= NN) { ok = 0; break; }
    }
    flags[0] = ok;
    const unsigned short* u = (const unsigned short*)xp;
    int crazy = 0;
    for (int i = 0; i < 256; ++i) {
        int ex = (u[i] >> 7) & 0xFF;
        if (ex == 0xFF || ex > 150) crazy++;
    }
    flags[1] = (crazy < 8) ? 1 : 0;
}

__device__ __forceinline__ int edge_at(const void* ei, int is64, size_t pos) {
    return is64 ? (int)((const i64*)ei)[pos] : ((const int*)ei)[pos];
}

__device__ __forceinline__ float fld(const void* p, int isbf, size_t i) {
    return isbf ? __bfloat162float(((const __hip_bfloat16*)p)[i])
                : ((const float*)p)[i];
}

// ---------------------------------------------------------------------------
// degree / normalization / CSR build
// ---------------------------------------------------------------------------
__global__ void count_deg(const void* __restrict__ ei, const int* __restrict__ flags,
                          int* __restrict__ deg, int E) {
    int e = blockIdx.x * 256 + threadIdx.x;
    if (e < E) atomicAdd(&deg[edge_at(ei, flags[0], (size_t)E + e)], 1);
}

__global__ void make_dis(const int* __restrict__ deg, float* __restrict__ dis, int n) {
    int i = blockIdx.x * 256 + threadIdx.x;
    if (i < n) dis[i] = rsqrtf((float)deg[i] + 1.0f);
}

// block-level exclusive scan of deg -> rowptr (within-block), block totals -> bsum
__global__ void scan_block(const int* __restrict__ deg, int* __restrict__ rowptr,
                           int* __restrict__ bsum, int n) {
    __shared__ int s[256];
    int i = blockIdx.x * 256 + threadIdx.x;
    int v = (i < n) ? deg[i] : 0;
    s[threadIdx.x] = v;
    __syncthreads();
    for (int off = 1; off < 256; off <<= 1) {
        int t = (threadIdx.x >= off) ? s[threadIdx.x - off] : 0;
        __syncthreads();
        s[threadIdx.x] += t;
        __syncthreads();
    }
    if (i < n) rowptr[i] = s[threadIdx.x] - v;
    if (threadIdx.x == 255) bsum[blockIdx.x] = s[255];
}

// exclusive scan of block totals, single block, chunked
__global__ void scan_totals(int* __restrict__ bsum, int nb) {
    __shared__ int s[256];
    __shared__ int carry;
    if (threadIdx.x == 0) carry = 0;
    __syncthreads();
    for (int base = 0; base < nb; base += 256) {
        int i = base + threadIdx.x;
        int v = (i < nb) ? bsum[i] : 0;
        s[threadIdx.x] = v;
        __syncthreads();
        for (int off = 1; off < 256; off <<= 1) {
            int t = (threadIdx.x >= off) ? s[threadIdx.x - off] : 0;
            __syncthreads();
            s[threadIdx.x] += t;
            __syncthreads();
        }
        int total = s[255];
        if (i < nb) bsum[i] = s[threadIdx.x] - v + carry;
        __syncthreads();
        if (threadIdx.x == 0) carry += total;
        __syncthreads();
    }
}

// add block offsets; init cursor; write rowptr[NN]
__global__ void scan_add(int* __restrict__ rowptr, const int* __restrict__ bsum,
                         const int* __restrict__ deg, int* __restrict__ cursor, int n) {
    int i = blockIdx.x * 256 + threadIdx.x;
    if (i < n) {
        int r = rowptr[i] + bsum[blockIdx.x];
        rowptr[i] = r;
        cursor[i] = r;
        if (i == n - 1) rowptr[n] = r + deg[i];
    }
}

__global__ void csr_fill(const void* __restrict__ ei, const int* __restrict__ flags,
                         int* __restrict__ cursor, int* __restrict__ csr_src, int E) {
    int e = blockIdx.x * 256 + threadIdx.x;
    if (e < E) {
        int f = flags[0];
        int s = edge_at(ei, f, (size_t)e);
        int d = edge_at(ei, f, (size_t)E + e);
        int pos = atomicAdd(&cursor[d], 1);
        csr_src[pos] = s;
    }
}

// ---------------------------------------------------------------------------
// layer linears: write hd[n][c] = (x @ W)[n][c] * dis[n]
// gather then computes tanh((sum_edges hd[s] + hd[n]) * dis[n] + b)
// ---------------------------------------------------------------------------
__global__ __launch_bounds__(256) void lin128x32(const void* __restrict__ x,
                                                 const void* __restrict__ W,
                                                 const int* __restrict__ flags,
                                                 const float* __restrict__ dis,
                                                 float* __restrict__ hd) {
    __shared__ float wS[128 * 32];
    __shared__ float xS[8][128];
    int tid = threadIdx.x;
    int isbf = flags[1];
    for (int i = tid; i < 128 * 32; i += 256) wS[i] = fld(W, isbf, i);
    int n0 = blockIdx.x * 8;
    for (int i = tid; i < 8 * 128; i += 256) {
        int r = i >> 7, c = i & 127;
        int n = n0 + r;
        xS[r][c] = (n < NN) ? fld(x, isbf, (size_t)n * 128 + c) : 0.f;
    }
    __syncthreads();
    int r = tid >> 5, c = tid & 31;
    int n = n0 + r;
    if (n < NN) {
        float acc = 0.f;
        #pragma unroll
        for (int k = 0; k < 128; ++k) acc += xS[r][k] * wS[k * 32 + c];
        hd[(size_t)n * 32 + c] = acc * dis[n];
    }
}

__global__ __launch_bounds__(256) void lin32x32(const float* __restrict__ xcat_in,
                                                int col0in,
                                                const void* __restrict__ W,
                                                const int* __restrict__ flags,
                                                const float* __restrict__ dis,
                                                float* __restrict__ hd) {
    __shared__ float wS[32 * 32];
    __shared__ float xS[8][32];
    int tid = threadIdx.x;
    int isbf = flags[1];
    for (int i = tid; i < 32 * 32; i += 256) wS[i] = fld(W, isbf, i);
    int r = tid >> 5, c = tid & 31;
    int n = blockIdx.x * 8 + r;
    xS[r][c] = (n < NN) ? xcat_in[(size_t)n * FCAT + col0in + c] : 0.f;
    __syncthreads();
    if (n < NN) {
        float acc = 0.f;
        #pragma unroll
        for (int k = 0; k < 32; ++k) acc += xS[r][k] * wS[k * 32 + c];
        hd[(size_t)n * 32 + c] = acc * dis[n];
    }
}

__global__ __launch_bounds__(256) void lin32x1(const float* __restrict__ xcat_in,
                                               const void* __restrict__ W,
                                               const int* __restrict__ flags,
                                               const float* __restrict__ dis,
                                               float* __restrict__ hd1) {
    __shared__ float wS[32];
    if (threadIdx.x < 32) wS[threadIdx.x] = fld(W, flags[1], threadIdx.x);
    __syncthreads();
    int n = blockIdx.x * 256 + threadIdx.x;
    if (n < NN) {
        const float* xr = xcat_in + (size_t)n * FCAT + 64;
        float acc = 0.f;
        #pragma unroll
        for (int k = 0; k < 32; ++k) acc += xr[k] * wS[k];
        hd1[n] = acc * dis[n];
    }
}

// ---------------------------------------------------------------------------
// CSR gather: 32 threads per node (one per channel), atomic-free.
// xcat[n, col0+c] = tanh((sum_j hd[src_j][c] + hd[n][c]) * dis[n] + b[c])
// ---------------------------------------------------------------------------
__global__ __launch_bounds__(256) void gather32(const int* __restrict__ rowptr,
                                                const int* __restrict__ csr_src,
                                                const float* __restrict__ dis,
                                                const float* __restrict__ hd,
                                                const void* __restrict__ b,
                                                const int* __restrict__ flags,
                                                float* __restrict__ xcat, int col0) {
    int grp = threadIdx.x >> 5;
    int c = threadIdx.x & 31;
    int n = blockIdx.x * 8 + grp;
    if (n >= NN) return;
    int r0 = rowptr[n], r1 = rowptr[n + 1];
    float acc = hd[(size_t)n * 32 + c];       // self-loop term (pre-scaled)
    int j = r0;
    for (; j + 3 < r1; j += 4) {
        int s0 = csr_src[j], s1 = csr_src[j + 1];
        int s2 = csr_src[j + 2], s3 = csr_src[j + 3];
        acc += hd[(size_t)s0 * 32 + c];
        acc += hd[(size_t)s1 * 32 + c];
        acc += hd[(size_t)s2 * 32 + c];
        acc += hd[(size_t)s3 * 32 + c];
    }
    for (; j < r1; ++j) acc += hd[(size_t)csr_src[j] * 32 + c];
    float v = acc * dis[n] + fld(b, flags[1], c);
    xcat[(size_t)n * FCAT + col0 + c] = tanhf(v);
}

__global__ __launch_bounds__(256) void gather1(const int* __restrict__ rowptr,
                                               const int* __restrict__ csr_src,
                                               const float* __restrict__ dis,
                                               const float* __restrict__ hd1,
                                               const void* __restrict__ b,
                                               const int* __restrict__ flags,
                                               float* __restrict__ xcat) {
    int n = blockIdx.x * 256 + threadIdx.x;
    if (n >= NN) return;
    int r0 = rowptr[n], r1 = rowptr[n + 1];
    float acc = hd1[n];
    int j = r0;
    for (; j + 3 < r1; j += 4) {
        int s0 = csr_src[j], s1 = csr_src[j + 1];
        int s2 = csr_src[j + 2], s3 = csr_src[j + 3];
        acc += hd1[s0] + hd1[s1] + hd1[s2] + hd1[s3];
    }
    for (; j < r1; ++j) acc += hd1[csr_src[j]];
    xcat[(size_t)n * FCAT + 96] = tanhf(acc * dis[n] + fld(b, flags[1], 0));
}

// ---------------------------------------------------------------------------
// fused head (unchanged from passing R10 version; >256-item lists are strided)
// ---------------------------------------------------------------------------
__device__ __forceinline__ bool before_desc(float av, int ai, float bv, int bi) {
    return (av > bv) || (av == bv && ai < bi);
}

__global__ __launch_bounds__(256) void head_kernel(
        const float* __restrict__ xcat, const int* __restrict__ flags,
        const void* __restrict__ w5, const void* __restrict__ b5,
        const void* __restrict__ w6, const void* __restrict__ b6,
        const void* __restrict__ fw1, const void* __restrict__ fb1,
        const void* __restrict__ fw2, const void* __restrict__ fb2,
        float* __restrict__ out) {
    __shared__ float sval[256];
    __shared__ int   sidx[256];
    __shared__ float tk[KTOP][101];
    __shared__ float w5S[16 * 97];
    __shared__ float b5S[16];
    __shared__ float w6S[32 * 80];
    __shared__ float b6S[32];
    __shared__ float o5[16][30];
    __shared__ float m6[16][15];
    __shared__ float t6[352];
    __shared__ float hfc[128];

    int g = blockIdx.x;
    int tid = threadIdx.x;
    int isbf = flags[1];

    for (int i = tid; i < 16 * 97; i += 256) w5S[i] = fld(w5, isbf, i);
    for (int i = tid; i < 32 * 80; i += 256) w6S[i] = fld(w6, isbf, i);
    if (tid < 16) b5S[tid] = fld(b5, isbf, tid);
    if (tid < 32) b6S[tid] = fld(b6, isbf, tid);

    float v = -INFINITY;
    if (tid < NPG) v = xcat[(size_t)(g * NPG + tid) * FCAT + 96];
    sval[tid] = v;
    sidx[tid] = tid;
    __syncthreads();

    for (int k = 2; k <= 256; k <<= 1) {
        for (int j = k >> 1; j > 0; j >>= 1) {
            int i = tid;
            int ixj = i ^ j;
            if (ixj > i) {
                float av = sval[i], bv = sval[ixj];
                int   ai = sidx[i], bi = sidx[ixj];
                bool dir = ((i & k) == 0);
                bool sw = dir ? before_desc(bv, bi, av, ai)
                              : before_desc(av, ai, bv, bi);
                if (sw) {
                    sval[i] = bv; sval[ixj] = av;
                    sidx[i] = bi; sidx[ixj] = ai;
                }
            }
            __syncthreads();
        }
    }

    for (int i = tid; i < KTOP * FCAT; i += 256) {
        int k = i / FCAT, f = i % FCAT;
        tk[k][f] = xcat[(size_t)(g * NPG + sidx[k]) * FCAT + f];
    }
    __syncthreads();

    for (int t = tid; t < 16 * 30; t += 256) {
        int o = t / 30, p = t % 30;
        float acc = b5S[o];
        #pragma unroll 4
        for (int f = 0; f < 97; ++f) acc += tk[p][f] * w5S[o * 97 + f];
        o5[o][p] = fmaxf(acc, 0.f);
    }
    __syncthreads();

    if (tid < 16 * 15) {
        int o = tid / 15, q = tid % 15;
        m6[o][q] = fmaxf(o5[o][2 * q], o5[o][2 * q + 1]);
    }
    __syncthreads();

    for (int t = tid; t < 32 * 11; t += 256) {
        int o = t / 11, p = t % 11;
        float acc = b6S[o];
        #pragma unroll
        for (int i = 0; i < 16; ++i)
            #pragma unroll
            for (int j = 0; j < 5; ++j)
                acc += m6[i][p + j] * w6S[o * 80 + i * 5 + j];
        t6[o * 11 + p] = fmaxf(acc, 0.f);
    }
    __syncthreads();

    if (tid < 128) {
        float acc = fld(fb1, isbf, tid);
        for (int i = 0; i < 352; ++i)
            acc += t6[i] * fld(fw1, isbf, (size_t)tid * 352 + i);
        hfc[tid] = fmaxf(acc, 0.f);
    }
    __syncthreads();

    if (tid < NCLS) {
        float acc = fld(fb2, isbf, tid);
        #pragma unroll 4
        for (int i = 0; i < 128; ++i)
            acc += hfc[i] * fld(fw2, isbf, (size_t)tid * 128 + i);
        out[g * NCLS + tid] = acc;
    }
}

// ---------------------------------------------------------------------------
// launch
// ---------------------------------------------------------------------------
extern "C" void kernel_launch(void* const* d_in, const int* in_sizes, int n_in,
                              void* d_out, int out_size, void* d_ws, size_t ws_size,
                              hipStream_t stream) {
    const void* x  = d_in[0];
    const void* ei = d_in[1];
    const void* W1 = d_in[3];  const void* b1 = d_in[4];
    const void* W2 = d_in[5];  const void* b2 = d_in[6];
    const void* W3 = d_in[7];  const void* b3 = d_in[8];
    const void* W4 = d_in[9];  const void* b4 = d_in[10];
    const void* w5 = d_in[11]; const void* b5 = d_in[12];
    const void* w6 = d_in[13]; const void* b6 = d_in[14];
    const void* fw1 = d_in[15]; const void* fb1 = d_in[16];
    const void* fw2 = d_in[17]; const void* fb2 = d_in[18];

    const int E = in_sizes[1] / 2;
    const int TB = 256;
    const int NB_N = (NN + TB - 1) / TB;   // 391

    // workspace carve-up (256B aligned): ~66.1 MB total
    char* ws = (char*)d_ws;
    auto alloc = [&](size_t bytes) {
        void* p = (void*)ws;
        ws += (bytes + 255) & ~(size_t)255;
        return p;
    };
    int*   flags  = (int*) alloc(256);
    int*   deg    = (int*) alloc((size_t)NN * 4);           // 0.4 MB
    float* dis    = (float*)alloc((size_t)NN * 4);          // 0.4 MB
    int*   rowptr = (int*) alloc((size_t)(NN + 1) * 4);     // 0.4 MB
    int*   bsum   = (int*) alloc((size_t)NB_N * 4);         // ~2 KB
    int*   cursor = (int*) alloc((size_t)NN * 4);           // 0.4 MB
    int*   csr_src= (int*) alloc((size_t)E * 4);            // 12.8 MB
    float* hd     = (float*)alloc((size_t)NN * 32 * 4);     // 12.8 MB
    float* xcat   = (float*)alloc((size_t)NN * FCAT * 4);   // 38.8 MB
    (void)ws_size; (void)n_in; (void)out_size;

    int nb_edges = (E + TB - 1) / TB;
    int nb_lin   = (NN + 7) / 8;
    int nb_g32   = (NN + 7) / 8;

    detect_dtypes<<<1, 64, 0, stream>>>(ei, x, flags);

    // CSR build
    hipMemsetAsync(deg, 0, (size_t)NN * 4, stream);
    count_deg<<<nb_edges, TB, 0, stream>>>(ei, flags, deg, E);
    make_dis<<<NB_N, TB, 0, stream>>>(deg, dis, NN);
    scan_block<<<NB_N, TB, 0, stream>>>(deg, rowptr, bsum, NN);
    scan_totals<<<1, TB, 0, stream>>>(bsum, NB_N);
    scan_add<<<NB_N, TB, 0, stream>>>(rowptr, bsum, deg, cursor, NN);
    csr_fill<<<nb_edges, TB, 0, stream>>>(ei, flags, cursor, csr_src, E);

    // layer 1: 128 -> 32 (cols 0..31)
    lin128x32<<<nb_lin, TB, 0, stream>>>(x, W1, flags, dis, hd);
    gather32<<<nb_g32, TB, 0, stream>>>(rowptr, csr_src, dis, hd, b1, flags, xcat, 0);

    // layer 2: 32 -> 32 (cols 32..63)
    lin32x32<<<nb_lin, TB, 0, stream>>>(xcat, 0, W2, flags, dis, hd);
    gather32<<<nb_g32, TB, 0, stream>>>(rowptr, csr_src, dis, hd, b2, flags, xcat, 32);

    // layer 3: 32 -> 32 (cols 64..95)
    lin32x32<<<nb_lin, TB, 0, stream>>>(xcat, 32, W3, flags, dis, hd);
    gather32<<<nb_g32, TB, 0, stream>>>(rowptr, csr_src, dis, hd, b3, flags, xcat, 64);

    // layer 4: 32 -> 1 (col 96)
    lin32x1<<<NB_N, TB, 0, stream>>>(xcat, W4, flags, dis, hd);
    gather1<<<NB_N, TB, 0, stream>>>(rowptr, csr_src, dis, hd, b4, flags, xcat);

    // fused head
    head_kernel<<<BG, TB, 0, stream>>>(xcat, flags, w5, b5, w6, b6,
                                       fw1, fb1, fw2, fb2,
                                       (float*)d_out);
}

// Round 12
// 813.399 us; speedup vs baseline: 7.3522x; 1.1394x over previous
//
#include <hip/hip_runtime.h>
#include <hip/hip_bf16.h>

#define NN 100000      // nodes
#define BG 500         // graphs
#define NPG 200        // nodes per graph
#define KTOP 30
#define FCAT 97
#define NCLS 10

#define NSLICE 8                       // XCD count on MI355X
#define SLICE_N ((NN + NSLICE - 1) / NSLICE)   // 12500 nodes per slice
#define CHUNKS 128                     // blocks per slice for sliced passes

typedef long long i64;

// ---------------------------------------------------------------------------
// runtime dtype probes: flags[0]=edges int64, flags[1]=floats bf16
// ---------------------------------------------------------------------------
__global__ void detect_dtypes(const void* __restrict__ ei, const void* __restrict__ xp,
                              int* __restrict__ flags) {
    if (threadIdx.x != 0) return;
    const i64* p = (const i64*)ei;
    int ok = 1;
    for (int i = 0; i < 64; ++i) {
        i64 v = p[i];
        if (v < 0 || v >= NN) { ok = 0; break; }
    }
    flags[0] = ok;
    const unsigned short* u = (const unsigned short*)xp;
    int crazy = 0;
    for (int i = 0; i < 256; ++i) {
        int ex = (u[i] >> 7) & 0xFF;
        if (ex == 0xFF || ex > 150) crazy++;
    }
    flags[1] = (crazy < 8) ? 1 : 0;
}

__device__ __forceinline__ int edge_at(const void* ei, int is64, size_t pos) {
    return is64 ? (int)((const i64*)ei)[pos] : ((const int*)ei)[pos];
}

__device__ __forceinline__ float fld(const void* p, int isbf, size_t i) {
    return isbf ? __bfloat162float(((const __hip_bfloat16*)p)[i])
                : ((const float*)p)[i];
}

// ---------------------------------------------------------------------------
// XCD-sliced degree count + CSR fill.
// slice = blockIdx.x & 7: consecutive blocks round-robin across the 8 XCDs, so
// each slice's counters / csr region stays in ONE XCD's L2 -> scattered 4B
// writes accumulate into full 64B lines before writeback (was 15x amplified).
// Correct regardless of actual block->XCD mapping (slices are disjoint).
// ---------------------------------------------------------------------------
__global__ __launch_bounds__(256) void count_deg_sliced(const void* __restrict__ ei,
                                                        const int* __restrict__ flags,
                                                        int* __restrict__ deg, int E) {
    int slice = blockIdx.x & (NSLICE - 1);
    int chunk = blockIdx.x >> 3;
    int lo = slice * SLICE_N;
    int hi = (lo + SLICE_N < NN) ? lo + SLICE_N : NN;
    int f = flags[0];
    int stride = (gridDim.x >> 3) * 256;
    for (int e = chunk * 256 + threadIdx.x; e < E; e += stride) {
        int d = edge_at(ei, f, (size_t)E + e);
        if (d >= lo && d < hi) atomicAdd(&deg[d], 1);
    }
}

__global__ __launch_bounds__(256) void csr_fill_sliced(const void* __restrict__ ei,
                                                       const int* __restrict__ flags,
                                                       int* __restrict__ cursor,
                                                       int* __restrict__ csr_src, int E) {
    int slice = blockIdx.x & (NSLICE - 1);
    int chunk = blockIdx.x >> 3;
    int lo = slice * SLICE_N;
    int hi = (lo + SLICE_N < NN) ? lo + SLICE_N : NN;
    int f = flags[0];
    int stride = (gridDim.x >> 3) * 256;
    for (int e = chunk * 256 + threadIdx.x; e < E; e += stride) {
        int d = edge_at(ei, f, (size_t)E + e);
        if (d >= lo && d < hi) {
            int s = edge_at(ei, f, (size_t)e);
            int pos = atomicAdd(&cursor[d], 1);
            csr_src[pos] = s;
        }
    }
}

__global__ void make_dis(const int* __restrict__ deg, float* __restrict__ dis, int n) {
    int i = blockIdx.x * 256 + threadIdx.x;
    if (i < n) dis[i] = rsqrtf((float)deg[i] + 1.0f);
}

// block-level exclusive scan of deg -> rowptr (within-block), block totals -> bsum
__global__ void scan_block(const int* __restrict__ deg, int* __restrict__ rowptr,
                           int* __restrict__ bsum, int n) {
    __shared__ int s[256];
    int i = blockIdx.x * 256 + threadIdx.x;
    int v = (i < n) ? deg[i] : 0;
    s[threadIdx.x] = v;
    __syncthreads();
    for (int off = 1; off < 256; off <<= 1) {
        int t = (threadIdx.x >= off) ? s[threadIdx.x - off] : 0;
        __syncthreads();
        s[threadIdx.x] += t;
        __syncthreads();
    }
    if (i < n) rowptr[i] = s[threadIdx.x] - v;
    if (threadIdx.x == 255) bsum[blockIdx.x] = s[255];
}

__global__ void scan_totals(int* __restrict__ bsum, int nb) {
    __shared__ int s[256];
    __shared__ int carry;
    if (threadIdx.x == 0) carry = 0;
    __syncthreads();
    for (int base = 0; base < nb; base += 256) {
        int i = base + threadIdx.x;
        int v = (i < nb) ? bsum[i] : 0;
        s[threadIdx.x] = v;
        __syncthreads();
        for (int off = 1; off < 256; off <<= 1) {
            int t = (threadIdx.x >= off) ? s[threadIdx.x - off] : 0;
            __syncthreads();
            s[threadIdx.x] += t;
            __syncthreads();
        }
        int total = s[255];
        if (i < nb) bsum[i] = s[threadIdx.x] - v + carry;
        __syncthreads();
        if (threadIdx.x == 0) carry += total;
        __syncthreads();
    }
}

__global__ void scan_add(int* __restrict__ rowptr, const int* __restrict__ bsum,
                         const int* __restrict__ deg, int* __restrict__ cursor, int n) {
    int i = blockIdx.x * 256 + threadIdx.x;
    if (i < n) {
        int r = rowptr[i] + bsum[blockIdx.x];
        rowptr[i] = r;
        cursor[i] = r;
        if (i == n - 1) rowptr[n] = r + deg[i];
    }
}

// ---------------------------------------------------------------------------
// layer linears: write hd[n][c] = (x @ W)[n][c] * dis[n]
// ---------------------------------------------------------------------------
__global__ __launch_bounds__(256) void lin128x32(const void* __restrict__ x,
                                                 const void* __restrict__ W,
                                                 const int* __restrict__ flags,
                                                 const float* __restrict__ dis,
                                                 float* __restrict__ hd) {
    __shared__ float wS[128 * 32];
    __shared__ float xS[8][128];
    int tid = threadIdx.x;
    int isbf = flags[1];
    for (int i = tid; i < 128 * 32; i += 256) wS[i] = fld(W, isbf, i);
    int n0 = blockIdx.x * 8;
    for (int i = tid; i < 8 * 128; i += 256) {
        int r = i >> 7, c = i & 127;
        int n = n0 + r;
        xS[r][c] = (n < NN) ? fld(x, isbf, (size_t)n * 128 + c) : 0.f;
    }
    __syncthreads();
    int r = tid >> 5, c = tid & 31;
    int n = n0 + r;
    if (n < NN) {
        float acc = 0.f;
        #pragma unroll
        for (int k = 0; k < 128; ++k) acc += xS[r][k] * wS[k * 32 + c];
        hd[(size_t)n * 32 + c] = acc * dis[n];
    }
}

__global__ __launch_bounds__(256) void lin32x32(const float* __restrict__ xcat_in,
                                                int col0in,
                                                const void* __restrict__ W,
                                                const int* __restrict__ flags,
                                                const float* __restrict__ dis,
                                                float* __restrict__ hd) {
    __shared__ float wS[32 * 32];
    __shared__ float xS[8][32];
    int tid = threadIdx.x;
    int isbf = flags[1];
    for (int i = tid; i < 32 * 32; i += 256) wS[i] = fld(W, isbf, i);
    int r = tid >> 5, c = tid & 31;
    int n = blockIdx.x * 8 + r;
    xS[r][c] = (n < NN) ? xcat_in[(size_t)n * FCAT + col0in + c] : 0.f;
    __syncthreads();
    if (n < NN) {
        float acc = 0.f;
        #pragma unroll
        for (int k = 0; k < 32; ++k) acc += xS[r][k] * wS[k * 32 + c];
        hd[(size_t)n * 32 + c] = acc * dis[n];
    }
}

__global__ __launch_bounds__(256) void lin32x1(const float* __restrict__ xcat_in,
                                               const void* __restrict__ W,
                                               const int* __restrict__ flags,
                                               const float* __restrict__ dis,
                                               float* __restrict__ hd1) {
    __shared__ float wS[32];
    if (threadIdx.x < 32) wS[threadIdx.x] = fld(W, flags[1], threadIdx.x);
    __syncthreads();
    int n = blockIdx.x * 256 + threadIdx.x;
    if (n < NN) {
        const float* xr = xcat_in + (size_t)n * FCAT + 64;
        float acc = 0.f;
        #pragma unroll
        for (int k = 0; k < 32; ++k) acc += xr[k] * wS[k];
        hd1[n] = acc * dis[n];
    }
}

// ---------------------------------------------------------------------------
// CSR gather: 32 threads per node (one per channel), atomic-free.
// ---------------------------------------------------------------------------
__global__ __launch_bounds__(256) void gather32(const int* __restrict__ rowptr,
                                                const int* __restrict__ csr_src,
                                                const float* __restrict__ dis,
                                                const float* __restrict__ hd,
                                                const void* __restrict__ b,
                                                const int* __restrict__ flags,
                                                float* __restrict__ xcat, int col0) {
    int grp = threadIdx.x >> 5;
    int c = threadIdx.x & 31;
    int n = blockIdx.x * 8 + grp;
    if (n >= NN) return;
    int r0 = rowptr[n], r1 = rowptr[n + 1];
    float acc = hd[(size_t)n * 32 + c];       // self-loop term (pre-scaled)
    int j = r0;
    for (; j + 3 < r1; j += 4) {
        int s0 = csr_src[j], s1 = csr_src[j + 1];
        int s2 = csr_src[j + 2], s3 = csr_src[j + 3];
        acc += hd[(size_t)s0 * 32 + c];
        acc += hd[(size_t)s1 * 32 + c];
        acc += hd[(size_t)s2 * 32 + c];
        acc += hd[(size_t)s3 * 32 + c];
    }
    for (; j < r1; ++j) acc += hd[(size_t)csr_src[j] * 32 + c];
    float v = acc * dis[n] + fld(b, flags[1], c);
    xcat[(size_t)n * FCAT + col0 + c] = tanhf(v);
}

__global__ __launch_bounds__(256) void gather1(const int* __restrict__ rowptr,
                                               const int* __restrict__ csr_src,
                                               const float* __restrict__ dis,
                                               const float* __restrict__ hd1,
                                               const void* __restrict__ b,
                                               const int* __restrict__ flags,
                                               float* __restrict__ xcat) {
    int n = blockIdx.x * 256 + threadIdx.x;
    if (n >= NN) return;
    int r0 = rowptr[n], r1 = rowptr[n + 1];
    float acc = hd1[n];
    int j = r0;
    for (; j + 3 < r1; j += 4) {
        int s0 = csr_src[j], s1 = csr_src[j + 1];
        int s2 = csr_src[j + 2], s3 = csr_src[j + 3];
        acc += hd1[s0] + hd1[s1] + hd1[s2] + hd1[s3];
    }
    for (; j < r1; ++j) acc += hd1[csr_src[j]];
    xcat[(size_t)n * FCAT + 96] = tanhf(acc * dis[n] + fld(b, flags[1], 0));
}

// ---------------------------------------------------------------------------
// fused head (unchanged; >256-item lists are strided)
// ---------------------------------------------------------------------------
__device__ __forceinline__ bool before_desc(float av, int ai, float bv, int bi) {
    return (av > bv) || (av == bv && ai < bi);
}

__global__ __launch_bounds__(256) void head_kernel(
        const float* __restrict__ xcat, const int* __restrict__ flags,
        const void* __restrict__ w5, const void* __restrict__ b5,
        const void* __restrict__ w6, const void* __restrict__ b6,
        const void* __restrict__ fw1, const void* __restrict__ fb1,
        const void* __restrict__ fw2, const void* __restrict__ fb2,
        float* __restrict__ out) {
    __shared__ float sval[256];
    __shared__ int   sidx[256];
    __shared__ float tk[KTOP][101];
    __shared__ float w5S[16 * 97];
    __shared__ float b5S[16];
    __shared__ float w6S[32 * 80];
    __shared__ float b6S[32];
    __shared__ float o5[16][30];
    __shared__ float m6[16][15];
    __shared__ float t6[352];
    __shared__ float hfc[128];

    int g = blockIdx.x;
    int tid = threadIdx.x;
    int isbf = flags[1];

    for (int i = tid; i < 16 * 97; i += 256) w5S[i] = fld(w5, isbf, i);
    for (int i = tid; i < 32 * 80; i += 256) w6S[i] = fld(w6, isbf, i);
    if (tid < 16) b5S[tid] = fld(b5, isbf, tid);
    if (tid < 32) b6S[tid] = fld(b6, isbf, tid);

    float v = -INFINITY;
    if (tid < NPG) v = xcat[(size_t)(g * NPG + tid) * FCAT + 96];
    sval[tid] = v;
    sidx[tid] = tid;
    __syncthreads();

    for (int k = 2; k <= 256; k <<= 1) {
        for (int j = k >> 1; j > 0; j >>= 1) {
            int i = tid;
            int ixj = i ^ j;
            if (ixj > i) {
                float av = sval[i], bv = sval[ixj];
                int   ai = sidx[i], bi = sidx[ixj];
                bool dir = ((i & k) == 0);
                bool sw = dir ? before_desc(bv, bi, av, ai)
                              : before_desc(av, ai, bv, bi);
                if (sw) {
                    sval[i] = bv; sval[ixj] = av;
                    sidx[i] = bi; sidx[ixj] = ai;
                }
            }
            __syncthreads();
        }
    }

    for (int i = tid; i < KTOP * FCAT; i += 256) {
        int k = i / FCAT, f = i % FCAT;
        tk[k][f] = xcat[(size_t)(g * NPG + sidx[k]) * FCAT + f];
    }
    __syncthreads();

    for (int t = tid; t < 16 * 30; t += 256) {
        int o = t / 30, p = t % 30;
        float acc = b5S[o];
        #pragma unroll 4
        for (int f = 0; f < 97; ++f) acc += tk[p][f] * w5S[o * 97 + f];
        o5[o][p] = fmaxf(acc, 0.f);
    }
    __syncthreads();

    if (tid < 16 * 15) {
        int o = tid / 15, q = tid % 15;
        m6[o][q] = fmaxf(o5[o][2 * q], o5[o][2 * q + 1]);
    }
    __syncthreads();

    for (int t = tid; t < 32 * 11; t += 256) {
        int o = t / 11, p = t % 11;
        float acc = b6S[o];
        #pragma unroll
        for (int i = 0; i < 16; ++i)
            #pragma unroll
            for (int j = 0; j < 5; ++j)
                acc += m6[i][p + j] * w6S[o * 80 + i * 5 + j];
        t6[o * 11 + p] = fmaxf(acc, 0.f);
    }
    __syncthreads();

    if (tid < 128) {
        float acc = fld(fb1, isbf, tid);
        for (int i = 0; i < 352; ++i)
            acc += t6[i] * fld(fw1, isbf, (size_t)tid * 352 + i);
        hfc[tid] = fmaxf(acc, 0.f);
    }
    __syncthreads();

    if (tid < NCLS) {
        float acc = fld(fb2, isbf, tid);
        #pragma unroll 4
        for (int i = 0; i < 128; ++i)
            acc += hfc[i] * fld(fw2, isbf, (size_t)tid * 128 + i);
        out[g * NCLS + tid] = acc;
    }
}

// ---------------------------------------------------------------------------
// launch
// ---------------------------------------------------------------------------
extern "C" void kernel_launch(void* const* d_in, const int* in_sizes, int n_in,
                              void* d_out, int out_size, void* d_ws, size_t ws_size,
                              hipStream_t stream) {
    const void* x  = d_in[0];
    const void* ei = d_in[1];
    const void* W1 = d_in[3];  const void* b1 = d_in[4];
    const void* W2 = d_in[5];  const void* b2 = d_in[6];
    const void* W3 = d_in[7];  const void* b3 = d_in[8];
    const void* W4 = d_in[9];  const void* b4 = d_in[10];
    const void* w5 = d_in[11]; const void* b5 = d_in[12];
    const void* w6 = d_in[13]; const void* b6 = d_in[14];
    const void* fw1 = d_in[15]; const void* fb1 = d_in[16];
    const void* fw2 = d_in[17]; const void* fb2 = d_in[18];

    const int E = in_sizes[1] / 2;
    const int TB = 256;
    const int NB_N = (NN + TB - 1) / TB;   // 391

    // workspace carve-up (256B aligned): ~66.1 MB total
    char* ws = (char*)d_ws;
    auto alloc = [&](size_t bytes) {
        void* p = (void*)ws;
        ws += (bytes + 255) & ~(size_t)255;
        return p;
    };
    int*   flags  = (int*) alloc(256);
    int*   deg    = (int*) alloc((size_t)NN * 4);
    float* dis    = (float*)alloc((size_t)NN * 4);
    int*   rowptr = (int*) alloc((size_t)(NN + 1) * 4);
    int*   bsum   = (int*) alloc((size_t)NB_N * 4);
    int*   cursor = (int*) alloc((size_t)NN * 4);
    int*   csr_src= (int*) alloc((size_t)E * 4);
    float* hd     = (float*)alloc((size_t)NN * 32 * 4);
    float* xcat   = (float*)alloc((size_t)NN * FCAT * 4);
    (void)ws_size; (void)n_in; (void)out_size;

    int nb_lin = (NN + 7) / 8;
    int nb_g32 = (NN + 7) / 8;
    int nb_sliced = NSLICE * CHUNKS;    // 1024 blocks: slice = bid & 7

    detect_dtypes<<<1, 64, 0, stream>>>(ei, x, flags);

    // CSR build (XCD-sliced count + fill)
    hipMemsetAsync(deg, 0, (size_t)NN * 4, stream);
    count_deg_sliced<<<nb_sliced, TB, 0, stream>>>(ei, flags, deg, E);
    make_dis<<<NB_N, TB, 0, stream>>>(deg, dis, NN);
    scan_block<<<NB_N, TB, 0, stream>>>(deg, rowptr, bsum, NN);
    scan_totals<<<1, TB, 0, stream>>>(bsum, NB_N);
    scan_add<<<NB_N, TB, 0, stream>>>(rowptr, bsum, deg, cursor, NN);
    csr_fill_sliced<<<nb_sliced, TB, 0, stream>>>(ei, flags, cursor, csr_src, E);

    // layer 1: 128 -> 32 (cols 0..31)
    lin128x32<<<nb_lin, TB, 0, stream>>>(x, W1, flags, dis, hd);
    gather32<<<nb_g32, TB, 0, stream>>>(rowptr, csr_src, dis, hd, b1, flags, xcat, 0);

    // layer 2: 32 -> 32 (cols 32..63)
    lin32x32<<<nb_lin, TB, 0, stream>>>(xcat, 0, W2, flags, dis, hd);
    gather32<<<nb_g32, TB, 0, stream>>>(rowptr, csr_src, dis, hd, b2, flags, xcat, 32);

    // layer 3: 32 -> 32 (cols 64..95)
    lin32x32<<<nb_lin, TB, 0, stream>>>(xcat, 32, W3, flags, dis, hd);
    gather32<<<nb_g32, TB, 0, stream>>>(rowptr, csr_src, dis, hd, b3, flags, xcat, 64);

    // layer 4: 32 -> 1 (col 96)
    lin32x1<<<NB_N, TB, 0, stream>>>(xcat, W4, flags, dis, hd);
    gather1<<<NB_N, TB, 0, stream>>>(rowptr, csr_src, dis, hd, b4, flags, xcat);

    // fused head
    head_kernel<<<BG, TB, 0, stream>>>(xcat, flags, w5, b5, w6, b6,
                                       fw1, fb1, fw2, fb2,
                                       (float*)d_out);
}

// Round 13
// 719.209 us; speedup vs baseline: 8.3151x; 1.1310x over previous
//
#include <hip/hip_runtime.h>
#include <hip/hip_bf16.h>

#define NN 100000      // nodes
#define BG 500         // graphs
#define NPG 200        // nodes per graph
#define KTOP 30
#define FCAT 97
#define NCLS 10

typedef long long i64;

// ---------------------------------------------------------------------------
// runtime dtype probes: flags[0]=edges int64, flags[1]=floats bf16
// ---------------------------------------------------------------------------
__global__ void detect_dtypes(const void* __restrict__ ei, const void* __restrict__ xp,
                              int* __restrict__ flags) {
    if (threadIdx.x != 0) return;
    const i64* p = (const i64*)ei;
    int ok = 1;
    for (int i = 0; i < 64; ++i) {
        i64 v = p[i];
        if (v < 0 || v >= NN) { ok = 0; break; }
    }
    flags[0] = ok;
    const unsigned short* u = (const unsigned short*)xp;
    int crazy = 0;
    for (int i = 0; i < 256; ++i) {
        int ex = (u[i] >> 7) & 0xFF;
        if (ex == 0xFF || ex > 150) crazy++;
    }
    flags[1] = (crazy < 8) ? 1 : 0;
}

__device__ __forceinline__ int edge_at(const void* ei, int is64, size_t pos) {
    return is64 ? (int)((const i64*)ei)[pos] : ((const int*)ei)[pos];
}

__device__ __forceinline__ float fld(const void* p, int isbf, size_t i) {
    return isbf ? __bfloat162float(((const __hip_bfloat16*)p)[i])
                : ((const float*)p)[i];
}

// ---------------------------------------------------------------------------
// CSR build, atomic-rank formulation:
//   pass 1: rank[e] = atomicAdd(&deg[dst[e]], 1)   (rank store is coalesced)
//   scan  : rowptr = exclusive_scan(deg)
//   pass 2: csr_src[rowptr[dst[e]] + rank[e]] = src[e]   (NO atomics)
// ---------------------------------------------------------------------------
__global__ __launch_bounds__(256) void count_deg_rank(const void* __restrict__ ei,
                                                      const int* __restrict__ flags,
                                                      int* __restrict__ deg,
                                                      int* __restrict__ rank, int E) {
    int e = blockIdx.x * 256 + threadIdx.x;
    if (e < E) {
        int d = edge_at(ei, flags[0], (size_t)E + e);
        rank[e] = atomicAdd(&deg[d], 1);
    }
}

__global__ __launch_bounds__(256) void csr_fill_rank(const void* __restrict__ ei,
                                                     const int* __restrict__ flags,
                                                     const int* __restrict__ rowptr,
                                                     const int* __restrict__ rank,
                                                     int* __restrict__ csr_src, int E) {
    int e = blockIdx.x * 256 + threadIdx.x;
    if (e < E) {
        int f = flags[0];
        int s = edge_at(ei, f, (size_t)e);
        int d = edge_at(ei, f, (size_t)E + e);
        csr_src[rowptr[d] + rank[e]] = s;
    }
}

__global__ void make_dis(const int* __restrict__ deg, float* __restrict__ dis, int n) {
    int i = blockIdx.x * 256 + threadIdx.x;
    if (i < n) dis[i] = rsqrtf((float)deg[i] + 1.0f);
}

// block-level exclusive scan of deg -> rowptr (within-block), block totals -> bsum
__global__ void scan_block(const int* __restrict__ deg, int* __restrict__ rowptr,
                           int* __restrict__ bsum, int n) {
    __shared__ int s[256];
    int i = blockIdx.x * 256 + threadIdx.x;
    int v = (i < n) ? deg[i] : 0;
    s[threadIdx.x] = v;
    __syncthreads();
    for (int off = 1; off < 256; off <<= 1) {
        int t = (threadIdx.x >= off) ? s[threadIdx.x - off] : 0;
        __syncthreads();
        s[threadIdx.x] += t;
        __syncthreads();
    }
    if (i < n) rowptr[i] = s[threadIdx.x] - v;
    if (threadIdx.x == 255) bsum[blockIdx.x] = s[255];
}

__global__ void scan_totals(int* __restrict__ bsum, int nb) {
    __shared__ int s[256];
    __shared__ int carry;
    if (threadIdx.x == 0) carry = 0;
    __syncthreads();
    for (int base = 0; base < nb; base += 256) {
        int i = base + threadIdx.x;
        int v = (i < nb) ? bsum[i] : 0;
        s[threadIdx.x] = v;
        __syncthreads();
        for (int off = 1; off < 256; off <<= 1) {
            int t = (threadIdx.x >= off) ? s[threadIdx.x - off] : 0;
            __syncthreads();
            s[threadIdx.x] += t;
            __syncthreads();
        }
        int total = s[255];
        if (i < nb) bsum[i] = s[threadIdx.x] - v + carry;
        __syncthreads();
        if (threadIdx.x == 0) carry += total;
        __syncthreads();
    }
}

__global__ void scan_add(int* __restrict__ rowptr, const int* __restrict__ bsum,
                         const int* __restrict__ deg, int n) {
    int i = blockIdx.x * 256 + threadIdx.x;
    if (i < n) {
        int r = rowptr[i] + bsum[blockIdx.x];
        rowptr[i] = r;
        if (i == n - 1) rowptr[n] = r + deg[i];
    }
}

// ---------------------------------------------------------------------------
// layer linears: write hd[n][c] = (x @ W)[n][c] * dis[n]
// ---------------------------------------------------------------------------
__global__ __launch_bounds__(256) void lin128x32(const void* __restrict__ x,
                                                 const void* __restrict__ W,
                                                 const int* __restrict__ flags,
                                                 const float* __restrict__ dis,
                                                 float* __restrict__ hd) {
    __shared__ float wS[128 * 32];
    __shared__ float xS[8][128];
    int tid = threadIdx.x;
    int isbf = flags[1];
    for (int i = tid; i < 128 * 32; i += 256) wS[i] = fld(W, isbf, i);
    int n0 = blockIdx.x * 8;
    for (int i = tid; i < 8 * 128; i += 256) {
        int r = i >> 7, c = i & 127;
        int n = n0 + r;
        xS[r][c] = (n < NN) ? fld(x, isbf, (size_t)n * 128 + c) : 0.f;
    }
    __syncthreads();
    int r = tid >> 5, c = tid & 31;
    int n = n0 + r;
    if (n < NN) {
        float acc = 0.f;
        #pragma unroll
        for (int k = 0; k < 128; ++k) acc += xS[r][k] * wS[k * 32 + c];
        hd[(size_t)n * 32 + c] = acc * dis[n];
    }
}

__global__ __launch_bounds__(256) void lin32x32(const float* __restrict__ xcat_in,
                                                int col0in,
                                                const void* __restrict__ W,
                                                const int* __restrict__ flags,
                                                const float* __restrict__ dis,
                                                float* __restrict__ hd) {
    __shared__ float wS[32 * 32];
    __shared__ float xS[8][32];
    int tid = threadIdx.x;
    int isbf = flags[1];
    for (int i = tid; i < 32 * 32; i += 256) wS[i] = fld(W, isbf, i);
    int r = tid >> 5, c = tid & 31;
    int n = blockIdx.x * 8 + r;
    xS[r][c] = (n < NN) ? xcat_in[(size_t)n * FCAT + col0in + c] : 0.f;
    __syncthreads();
    if (n < NN) {
        float acc = 0.f;
        #pragma unroll
        for (int k = 0; k < 32; ++k) acc += xS[r][k] * wS[k * 32 + c];
        hd[(size_t)n * 32 + c] = acc * dis[n];
    }
}

__global__ __launch_bounds__(256) void lin32x1(const float* __restrict__ xcat_in,
                                               const void* __restrict__ W,
                                               const int* __restrict__ flags,
                                               const float* __restrict__ dis,
                                               float* __restrict__ hd1) {
    __shared__ float wS[32];
    if (threadIdx.x < 32) wS[threadIdx.x] = fld(W, flags[1], threadIdx.x);
    __syncthreads();
    int n = blockIdx.x * 256 + threadIdx.x;
    if (n < NN) {
        const float* xr = xcat_in + (size_t)n * FCAT + 64;
        float acc = 0.f;
        #pragma unroll
        for (int k = 0; k < 32; ++k) acc += xr[k] * wS[k];
        hd1[n] = acc * dis[n];
    }
}

// ---------------------------------------------------------------------------
// CSR gather: 32 threads per node (one per channel), atomic-free.
// ---------------------------------------------------------------------------
__global__ __launch_bounds__(256) void gather32(const int* __restrict__ rowptr,
                                                const int* __restrict__ csr_src,
                                                const float* __restrict__ dis,
                                                const float* __restrict__ hd,
                                                const void* __restrict__ b,
                                                const int* __restrict__ flags,
                                                float* __restrict__ xcat, int col0) {
    int grp = threadIdx.x >> 5;
    int c = threadIdx.x & 31;
    int n = blockIdx.x * 8 + grp;
    if (n >= NN) return;
    int r0 = rowptr[n], r1 = rowptr[n + 1];
    float acc = hd[(size_t)n * 32 + c];       // self-loop term (pre-scaled)
    int j = r0;
    for (; j + 3 < r1; j += 4) {
        int s0 = csr_src[j], s1 = csr_src[j + 1];
        int s2 = csr_src[j + 2], s3 = csr_src[j + 3];
        acc += hd[(size_t)s0 * 32 + c];
        acc += hd[(size_t)s1 * 32 + c];
        acc += hd[(size_t)s2 * 32 + c];
        acc += hd[(size_t)s3 * 32 + c];
    }
    for (; j < r1; ++j) acc += hd[(size_t)csr_src[j] * 32 + c];
    float v = acc * dis[n] + fld(b, flags[1], c);
    xcat[(size_t)n * FCAT + col0 + c] = tanhf(v);
}

__global__ __launch_bounds__(256) void gather1(const int* __restrict__ rowptr,
                                               const int* __restrict__ csr_src,
                                               const float* __restrict__ dis,
                                               const float* __restrict__ hd1,
                                               const void* __restrict__ b,
                                               const int* __restrict__ flags,
                                               float* __restrict__ xcat) {
    int n = blockIdx.x * 256 + threadIdx.x;
    if (n >= NN) return;
    int r0 = rowptr[n], r1 = rowptr[n + 1];
    float acc = hd1[n];
    int j = r0;
    for (; j + 3 < r1; j += 4) {
        int s0 = csr_src[j], s1 = csr_src[j + 1];
        int s2 = csr_src[j + 2], s3 = csr_src[j + 3];
        acc += hd1[s0] + hd1[s1] + hd1[s2] + hd1[s3];
    }
    for (; j < r1; ++j) acc += hd1[csr_src[j]];
    xcat[(size_t)n * FCAT + 96] = tanhf(acc * dis[n] + fld(b, flags[1], 0));
}

// ---------------------------------------------------------------------------
// fused head (unchanged; >256-item lists are strided)
// ---------------------------------------------------------------------------
__device__ __forceinline__ bool before_desc(float av, int ai, float bv, int bi) {
    return (av > bv) || (av == bv && ai < bi);
}

__global__ __launch_bounds__(256) void head_kernel(
        const float* __restrict__ xcat, const int* __restrict__ flags,
        const void* __restrict__ w5, const void* __restrict__ b5,
        const void* __restrict__ w6, const void* __restrict__ b6,
        const void* __restrict__ fw1, const void* __restrict__ fb1,
        const void* __restrict__ fw2, const void* __restrict__ fb2,
        float* __restrict__ out) {
    __shared__ float sval[256];
    __shared__ int   sidx[256];
    __shared__ float tk[KTOP][101];
    __shared__ float w5S[16 * 97];
    __shared__ float b5S[16];
    __shared__ float w6S[32 * 80];
    __shared__ float b6S[32];
    __shared__ float o5[16][30];
    __shared__ float m6[16][15];
    __shared__ float t6[352];
    __shared__ float hfc[128];

    int g = blockIdx.x;
    int tid = threadIdx.x;
    int isbf = flags[1];

    for (int i = tid; i < 16 * 97; i += 256) w5S[i] = fld(w5, isbf, i);
    for (int i = tid; i < 32 * 80; i += 256) w6S[i] = fld(w6, isbf, i);
    if (tid < 16) b5S[tid] = fld(b5, isbf, tid);
    if (tid < 32) b6S[tid] = fld(b6, isbf, tid);

    float v = -INFINITY;
    if (tid < NPG) v = xcat[(size_t)(g * NPG + tid) * FCAT + 96];
    sval[tid] = v;
    sidx[tid] = tid;
    __syncthreads();

    for (int k = 2; k <= 256; k <<= 1) {
        for (int j = k >> 1; j > 0; j >>= 1) {
            int i = tid;
            int ixj = i ^ j;
            if (ixj > i) {
                float av = sval[i], bv = sval[ixj];
                int   ai = sidx[i], bi = sidx[ixj];
                bool dir = ((i & k) == 0);
                bool sw = dir ? before_desc(bv, bi, av, ai)
                              : before_desc(av, ai, bv, bi);
                if (sw) {
                    sval[i] = bv; sval[ixj] = av;
                    sidx[i] = bi; sidx[ixj] = ai;
                }
            }
            __syncthreads();
        }
    }

    for (int i = tid; i < KTOP * FCAT; i += 256) {
        int k = i / FCAT, f = i % FCAT;
        tk[k][f] = xcat[(size_t)(g * NPG + sidx[k]) * FCAT + f];
    }
    __syncthreads();

    for (int t = tid; t < 16 * 30; t += 256) {
        int o = t / 30, p = t % 30;
        float acc = b5S[o];
        #pragma unroll 4
        for (int f = 0; f < 97; ++f) acc += tk[p][f] * w5S[o * 97 + f];
        o5[o][p] = fmaxf(acc, 0.f);
    }
    __syncthreads();

    if (tid < 16 * 15) {
        int o = tid / 15, q = tid % 15;
        m6[o][q] = fmaxf(o5[o][2 * q], o5[o][2 * q + 1]);
    }
    __syncthreads();

    for (int t = tid; t < 32 * 11; t += 256) {
        int o = t / 11, p = t % 11;
        float acc = b6S[o];
        #pragma unroll
        for (int i = 0; i < 16; ++i)
            #pragma unroll
            for (int j = 0; j < 5; ++j)
                acc += m6[i][p + j] * w6S[o * 80 + i * 5 + j];
        t6[o * 11 + p] = fmaxf(acc, 0.f);
    }
    __syncthreads();

    if (tid < 128) {
        float acc = fld(fb1, isbf, tid);
        for (int i = 0; i < 352; ++i)
            acc += t6[i] * fld(fw1, isbf, (size_t)tid * 352 + i);
        hfc[tid] = fmaxf(acc, 0.f);
    }
    __syncthreads();

    if (tid < NCLS) {
        float acc = fld(fb2, isbf, tid);
        #pragma unroll 4
        for (int i = 0; i < 128; ++i)
            acc += hfc[i] * fld(fw2, isbf, (size_t)tid * 128 + i);
        out[g * NCLS + tid] = acc;
    }
}

// ---------------------------------------------------------------------------
// launch
// ---------------------------------------------------------------------------
extern "C" void kernel_launch(void* const* d_in, const int* in_sizes, int n_in,
                              void* d_out, int out_size, void* d_ws, size_t ws_size,
                              hipStream_t stream) {
    const void* x  = d_in[0];
    const void* ei = d_in[1];
    const void* W1 = d_in[3];  const void* b1 = d_in[4];
    const void* W2 = d_in[5];  const void* b2 = d_in[6];
    const void* W3 = d_in[7];  const void* b3 = d_in[8];
    const void* W4 = d_in[9];  const void* b4 = d_in[10];
    const void* w5 = d_in[11]; const void* b5 = d_in[12];
    const void* w6 = d_in[13]; const void* b6 = d_in[14];
    const void* fw1 = d_in[15]; const void* fb1 = d_in[16];
    const void* fw2 = d_in[17]; const void* fb2 = d_in[18];

    const int E = in_sizes[1] / 2;
    const int TB = 256;
    const int NB_N = (NN + TB - 1) / TB;   // 391

    // workspace carve-up (256B aligned): ~66 MB total (rank aliases hd)
    char* ws = (char*)d_ws;
    auto alloc = [&](size_t bytes) {
        void* p = (void*)ws;
        ws += (bytes + 255) & ~(size_t)255;
        return p;
    };
    int*   flags  = (int*) alloc(256);
    int*   deg    = (int*) alloc((size_t)NN * 4);
    float* dis    = (float*)alloc((size_t)NN * 4);
    int*   rowptr = (int*) alloc((size_t)(NN + 1) * 4);
    int*   bsum   = (int*) alloc((size_t)NB_N * 4);
    int*   csr_src= (int*) alloc((size_t)E * 4);            // 12.8 MB
    float* hd     = (float*)alloc((size_t)NN * 32 * 4);     // 12.8 MB
    float* xcat   = (float*)alloc((size_t)NN * FCAT * 4);   // 38.8 MB
    int*   rank   = (int*)hd;   // alias: rank[E] dead before hd first written
    (void)ws_size; (void)n_in; (void)out_size;

    int nb_edges = (E + TB - 1) / TB;
    int nb_lin   = (NN + 7) / 8;
    int nb_g32   = (NN + 7) / 8;

    detect_dtypes<<<1, 64, 0, stream>>>(ei, x, flags);

    // CSR build (atomic-rank, fill is atomic-free)
    hipMemsetAsync(deg, 0, (size_t)NN * 4, stream);
    count_deg_rank<<<nb_edges, TB, 0, stream>>>(ei, flags, deg, rank, E);
    make_dis<<<NB_N, TB, 0, stream>>>(deg, dis, NN);
    scan_block<<<NB_N, TB, 0, stream>>>(deg, rowptr, bsum, NN);
    scan_totals<<<1, TB, 0, stream>>>(bsum, NB_N);
    scan_add<<<NB_N, TB, 0, stream>>>(rowptr, bsum, deg, NN);
    csr_fill_rank<<<nb_edges, TB, 0, stream>>>(ei, flags, rowptr, rank, csr_src, E);

    // layer 1: 128 -> 32 (cols 0..31)
    lin128x32<<<nb_lin, TB, 0, stream>>>(x, W1, flags, dis, hd);
    gather32<<<nb_g32, TB, 0, stream>>>(rowptr, csr_src, dis, hd, b1, flags, xcat, 0);

    // layer 2: 32 -> 32 (cols 32..63)
    lin32x32<<<nb_lin, TB, 0, stream>>>(xcat, 0, W2, flags, dis, hd);
    gather32<<<nb_g32, TB, 0, stream>>>(rowptr, csr_src, dis, hd, b2, flags, xcat, 32);

    // layer 3: 32 -> 32 (cols 64..95)
    lin32x32<<<nb_lin, TB, 0, stream>>>(xcat, 32, W3, flags, dis, hd);
    gather32<<<nb_g32, TB, 0, stream>>>(rowptr, csr_src, dis, hd, b3, flags, xcat, 64);

    // layer 4: 32 -> 1 (col 96)
    lin32x1<<<NB_N, TB, 0, stream>>>(xcat, W4, flags, dis, hd);
    gather1<<<NB_N, TB, 0, stream>>>(rowptr, csr_src, dis, hd, b4, flags, xcat);

    // fused head
    head_kernel<<<BG, TB, 0, stream>>>(xcat, flags, w5, b5, w6, b6,
                                       fw1, fb1, fw2, fb2,
                                       (float*)d_out);
}